// Round 1
// baseline (30895.416 us; speedup 1.0000x reference)
//
#include <hip/hip_runtime.h>

constexpr int TSTEPS = 512;
constexpr int BROWS  = 32;            // rows per block
constexpr int LPR    = 8;             // lanes per row
constexpr int BLOCK  = BROWS * LPR;   // 256 threads

__device__ __forceinline__ float silu_f(float x) {
    // x * sigmoid(x) = x / (1 + e^-x); safe at +-inf ranges (exp->inf => ratio->+-0)
    return x / (1.0f + __expf(-x));
}

__global__ __launch_bounds__(BLOCK, 2)
void odernn_fp32(const float* __restrict__ quat,
                 const float* __restrict__ W1, const float* __restrict__ b1,
                 const float* __restrict__ W2, const float* __restrict__ b2,
                 const float* __restrict__ W3, const float* __restrict__ b3,
                 float* __restrict__ out)
{
    __shared__ float sW1[8 * 128];
    __shared__ float sb1[128];
    __shared__ float sW2[128 * 128];
    __shared__ float sb2[128];
    __shared__ float sW3[128 * 4];
    __shared__ float sb3[4];

    for (int i = threadIdx.x; i < 8 * 128;   i += BLOCK) sW1[i] = W1[i];
    for (int i = threadIdx.x; i < 128;       i += BLOCK) sb1[i] = b1[i];
    for (int i = threadIdx.x; i < 128 * 128; i += BLOCK) sW2[i] = W2[i];
    for (int i = threadIdx.x; i < 128;       i += BLOCK) sb2[i] = b2[i];
    for (int i = threadIdx.x; i < 128 * 4;   i += BLOCK) sW3[i] = W3[i];
    for (int i = threadIdx.x; i < 4;         i += BLOCK) sb3[i] = b3[i];
    __syncthreads();

    const int lane  = threadIdx.x & 63;
    const int part  = threadIdx.x & 7;       // 8 lanes per row
    const int rbase = lane & ~7;             // first lane of this row's group
    const int row   = blockIdx.x * BROWS + (threadIdx.x >> 3);
    const int j0    = part * 4;              // lane owns j = m*32 + j0 + c  (m,c in 0..3)

    // bias b3 to regs (tiny)
    float b3r[4];
    #pragma unroll
    for (int c = 0; c < 4; ++c) b3r[c] = sb3[c];

    float h[4] = {1.0f, 0.0f, 0.0f, 0.0f};
    float k1[4], k2[4], k3[4];
    #pragma unroll
    for (int d = 0; d < 4; ++d) { k1[d] = 0.f; k2[d] = 0.f; k3[d] = 0.f; }

    const float* qptr = quat + ((size_t)row * TSTEPS) * 4;

    #pragma unroll 1
    for (int t = 0; t < TSTEPS; ++t) {
        const float4 qv = *reinterpret_cast<const float4*>(qptr + t * 4);
        const float q[4] = {qv.x, qv.y, qv.z, qv.w};

        float hnew[4] = {0.f, 0.f, 0.f, 0.f};

        #pragma unroll 1
        for (int s = 0; s < 4; ++s) {
            // stage input (3/8-rule RK4)
            float hc[4];
            #pragma unroll
            for (int d = 0; d < 4; ++d) {
                float v = h[d];
                if (s == 1)      v += (1.0f / 3.0f) * k1[d];
                else if (s == 2) v += k2[d] - (1.0f / 3.0f) * k1[d];
                else if (s == 3) v += k1[d] - k2[d] + k3[d];
                hc[d] = v;
            }

            // ---- layer 1: x1r[m*4+c] = silu(b1[j] + sum_k xin[k]*W1[k][j]) ----
            float x1r[16];
            #pragma unroll
            for (int m = 0; m < 4; ++m) {
                float4 a = *reinterpret_cast<const float4*>(&sb1[m * 32 + j0]);
                #pragma unroll
                for (int k = 0; k < 8; ++k) {
                    const float xk = (k < 4) ? hc[k] : q[k - 4];
                    const float4 w = *reinterpret_cast<const float4*>(&sW1[k * 128 + m * 32 + j0]);
                    a.x = fmaf(xk, w.x, a.x);
                    a.y = fmaf(xk, w.y, a.y);
                    a.z = fmaf(xk, w.z, a.z);
                    a.w = fmaf(xk, w.w, a.w);
                }
                x1r[m * 4 + 0] = silu_f(a.x);
                x1r[m * 4 + 1] = silu_f(a.y);
                x1r[m * 4 + 2] = silu_f(a.z);
                x1r[m * 4 + 3] = silu_f(a.w);
            }

            // ---- layer 2: acc[m*4+c] = b2[j] + sum_k x1[k]*W2[k][j] ----
            float acc[16];
            #pragma unroll
            for (int m = 0; m < 4; ++m) {
                const float4 bv = *reinterpret_cast<const float4*>(&sb2[m * 32 + j0]);
                acc[m * 4 + 0] = bv.x; acc[m * 4 + 1] = bv.y;
                acc[m * 4 + 2] = bv.z; acc[m * 4 + 3] = bv.w;
            }
            #pragma unroll
            for (int mk = 0; mk < 4; ++mk) {
                #pragma unroll 1
                for (int pk = 0; pk < 8; ++pk) {       // rolled: pk only feeds addresses/lane ids
                    const float* wrow = &sW2[(mk * 32 + pk * 4) * 128 + j0];
                    #pragma unroll
                    for (int ck = 0; ck < 4; ++ck) {
                        // k = mk*32 + pk*4 + ck ; owner lane = rbase + pk ; reg idx = mk*4+ck
                        const float xk = __shfl(x1r[mk * 4 + ck], rbase + pk, 64);
                        #pragma unroll
                        for (int m = 0; m < 4; ++m) {
                            const float4 w = *reinterpret_cast<const float4*>(&wrow[ck * 128 + m * 32]);
                            acc[m * 4 + 0] = fmaf(xk, w.x, acc[m * 4 + 0]);
                            acc[m * 4 + 1] = fmaf(xk, w.y, acc[m * 4 + 1]);
                            acc[m * 4 + 2] = fmaf(xk, w.z, acc[m * 4 + 2]);
                            acc[m * 4 + 3] = fmaf(xk, w.w, acc[m * 4 + 3]);
                        }
                    }
                }
            }

            // ---- layer 3 partials: p[c'] = sum_{my j} silu(acc)*W3[j][c'] ----
            float p[4] = {0.f, 0.f, 0.f, 0.f};
            #pragma unroll
            for (int m = 0; m < 4; ++m) {
                #pragma unroll
                for (int c = 0; c < 4; ++c) {
                    const int j = m * 32 + j0 + c;
                    const float xv = silu_f(acc[m * 4 + c]);
                    const float4 w = *reinterpret_cast<const float4*>(&sW3[j * 4]);
                    p[0] = fmaf(xv, w.x, p[0]);
                    p[1] = fmaf(xv, w.y, p[1]);
                    p[2] = fmaf(xv, w.z, p[2]);
                    p[3] = fmaf(xv, w.w, p[3]);
                }
            }
            // butterfly allreduce across the row's 8 lanes (bitwise-symmetric)
            #pragma unroll
            for (int mx = 1; mx < 8; mx <<= 1) {
                #pragma unroll
                for (int c = 0; c < 4; ++c) p[c] += __shfl_xor(p[c], mx, 64);
            }

            float kk[4];
            #pragma unroll
            for (int c = 0; c < 4; ++c) kk[c] = p[c] + b3r[c];

            const float wgt = (s == 1 || s == 2) ? 0.375f : 0.125f;
            #pragma unroll
            for (int d = 0; d < 4; ++d) hnew[d] += wgt * kk[d];

            if (s == 0) {
                #pragma unroll
                for (int d = 0; d < 4; ++d) k1[d] = kk[d];
            } else if (s == 1) {
                #pragma unroll
                for (int d = 0; d < 4; ++d) k2[d] = kk[d];
            } else if (s == 2) {
                #pragma unroll
                for (int d = 0; d < 4; ++d) k3[d] = kk[d];
            }
        }

        #pragma unroll
        for (int d = 0; d < 4; ++d) h[d] += hnew[d];
    }

    if (part == 0) {
        float4 o = {h[0], h[1], h[2], h[3]};
        *reinterpret_cast<float4*>(out + (size_t)row * 4) = o;
    }
}

extern "C" void kernel_launch(void* const* d_in, const int* in_sizes, int n_in,
                              void* d_out, int out_size, void* d_ws, size_t ws_size,
                              hipStream_t stream)
{
    const float* quat = (const float*)d_in[0];
    const float* W1   = (const float*)d_in[1];
    const float* b1   = (const float*)d_in[2];
    const float* W2   = (const float*)d_in[3];
    const float* b2   = (const float*)d_in[4];
    const float* W3   = (const float*)d_in[5];
    const float* b3   = (const float*)d_in[6];
    float* out        = (float*)d_out;

    const int B = in_sizes[0] / (TSTEPS * 4);      // 16384
    dim3 grid(B / BROWS), block(BLOCK);
    hipLaunchKernelGGL(odernn_fp32, grid, block, 0, stream,
                       quat, W1, b1, W2, b2, W3, b3, out);
}

// Round 2
// 11337.103 us; speedup vs baseline: 2.7252x; 2.7252x over previous
//
#include <hip/hip_runtime.h>

typedef float f32x4 __attribute__((ext_vector_type(4)));
typedef short short8v __attribute__((ext_vector_type(8)));

constexpr int TSTEPS = 512;

__device__ __forceinline__ float silu_f(float x) {
    // x * sigmoid(x); safe for |x| large: exp->inf => x/inf -> +-0, exp->0 => x
    return x / (1.0f + __expf(-x));
}

// 3-term bf16 split by truncation: x = hi + mid + lo (+ residual ~2^-24 |x|).
// Subtractions are exact (removing top mantissa bits).
__device__ __forceinline__ void split3(float x, short &s0, short &s1, short &s2) {
    unsigned u1 = __float_as_uint(x) & 0xFFFF0000u;
    float r1 = x - __uint_as_float(u1);
    unsigned u2 = __float_as_uint(r1) & 0xFFFF0000u;
    float r2 = r1 - __uint_as_float(u2);
    s0 = (short)(u1 >> 16);
    s1 = (short)(u2 >> 16);
    s2 = (short)(__float_as_uint(r2) >> 16);
}

// 6-product triple-split MFMA: error ~2^-26 relative (drops mid*lo, lo*mid, lo*lo)
__device__ __forceinline__ f32x4 mfma6(const short8v *A, const short8v *B, f32x4 c) {
    c = __builtin_amdgcn_mfma_f32_16x16x32_bf16(A[0], B[0], c, 0, 0, 0);
    c = __builtin_amdgcn_mfma_f32_16x16x32_bf16(A[0], B[1], c, 0, 0, 0);
    c = __builtin_amdgcn_mfma_f32_16x16x32_bf16(A[1], B[0], c, 0, 0, 0);
    c = __builtin_amdgcn_mfma_f32_16x16x32_bf16(A[0], B[2], c, 0, 0, 0);
    c = __builtin_amdgcn_mfma_f32_16x16x32_bf16(A[1], B[1], c, 0, 0, 0);
    c = __builtin_amdgcn_mfma_f32_16x16x32_bf16(A[2], B[0], c, 0, 0, 0);
    return c;
}

// Block: 256 threads = 4 waves, 16 rows per block.
// Orientation "batch-as-N": C[j][b] = sum_k W[k][j] * X[k][b]
//   A-operand = W^T fragments (weights, persistent in VGPRs)
//   B-operand = activations; C: col(lane&15)=batch b, row=(lane>>4)*4+reg = j
// K-split: wave w owns k in [32w, 32w+32) for layer2/layer3 (partials reduced via LDS);
// layer1 is M-split (wave w computes j in [32w, 32w+32) fully; K=8 zero-padded to 32).
__global__ __launch_bounds__(256, 2)
void odernn_mfma(const float* __restrict__ quat,
                 const float* __restrict__ W1, const float* __restrict__ b1,
                 const float* __restrict__ W2, const float* __restrict__ b2,
                 const float* __restrict__ W3, const float* __restrict__ b3,
                 float* __restrict__ out)
{
    __shared__ float sx1[16][132];      // x1 (post-silu), [batch][j], pitch 132 -> uniform b128 bank slots
    __shared__ float sx2p[4][16][132];  // layer2 partial sums per wave
    __shared__ float sk3[4][16][4];     // layer3 partial sums per wave
    __shared__ float sb1[128];
    __shared__ float sb2[128];

    const int tid  = threadIdx.x;
    const int w    = tid >> 6;     // wave id 0..3
    const int lane = tid & 63;
    const int l15  = lane & 15;    // batch col (B/C operands) or M-row (A operand)
    const int g    = lane >> 4;    // k-subgroup: k-in-tile = 8g+e
    const int rowbase = blockIdx.x * 16;

    if (tid < 128) { sb1[tid] = b1[tid]; sb2[tid] = b2[tid]; }

    // ---- one-time: load + triple-split weights into A-fragments ----
    short8v A2[8][3];   // W2^T: A[m=j][k], j = 16*mt + l15, k = 32w + 8g + e
    #pragma unroll
    for (int mt = 0; mt < 8; ++mt) {
        #pragma unroll
        for (int e = 0; e < 8; ++e) {
            float x = W2[(32*w + 8*g + e) * 128 + (16*mt + l15)];
            short t0, t1, t2; split3(x, t0, t1, t2);
            A2[mt][0][e] = t0; A2[mt][1][e] = t1; A2[mt][2][e] = t2;
        }
    }
    short8v A1[2][3];   // W1^T: j = 32w + 16mt + l15, k = 8g+e (real only k<8)
    #pragma unroll
    for (int mt = 0; mt < 2; ++mt) {
        #pragma unroll
        for (int e = 0; e < 8; ++e) {
            int k = 8*g + e;
            float x = (k < 8) ? W1[k * 128 + (32*w + 16*mt + l15)] : 0.0f;
            short t0, t1, t2; split3(x, t0, t1, t2);
            A1[mt][0][e] = t0; A1[mt][1][e] = t1; A1[mt][2][e] = t2;
        }
    }
    short8v A3[3];      // W3^T: m-row = j' (<4, else zero), k = 32w + 8g + e
    #pragma unroll
    for (int e = 0; e < 8; ++e) {
        float x = (l15 < 4) ? W3[(32*w + 8*g + e) * 4 + l15] : 0.0f;
        short t0, t1, t2; split3(x, t0, t1, t2);
        A3[0][e] = t0; A3[1][e] = t1; A3[2][e] = t2;
    }
    f32x4 b3v;
    { const f32x4* p = (const f32x4*)b3; b3v = *p; }

    __syncthreads();

    f32x4 h  = {1.0f, 0.0f, 0.0f, 0.0f};
    f32x4 k1 = {0,0,0,0}, k2 = {0,0,0,0}, k3v = {0,0,0,0};
    const float* qp = quat + (size_t)(rowbase + l15) * TSTEPS * 4;

    #pragma unroll 1
    for (int t = 0; t < TSTEPS; ++t) {
        f32x4 q = *(const f32x4*)(qp + 4 * t);
        f32x4 hnew = {0,0,0,0};

        #pragma unroll 1
        for (int s = 0; s < 4; ++s) {
            // RK4 (3/8-rule) stage input
            f32x4 hs = h;
            if (s == 1)      hs += k1 * (1.0f/3.0f);
            else if (s == 2) hs += k2 - k1 * (1.0f/3.0f);
            else if (s == 3) hs += k1 - k2 + k3v;

            // ---- layer 1: B-frag from local [hs, q] (k<8 real; g>0 lanes zero) ----
            short8v B0[3];
            {
                float xv[8] = {hs.x, hs.y, hs.z, hs.w, q.x, q.y, q.z, q.w};
                #pragma unroll
                for (int e = 0; e < 8; ++e) {
                    float x = (g == 0) ? xv[e] : 0.0f;
                    short t0, t1, t2; split3(x, t0, t1, t2);
                    B0[0][e] = t0; B0[1][e] = t1; B0[2][e] = t2;
                }
            }
            f32x4 c1[2];
            c1[0] = *(const f32x4*)&sb1[32*w + 4*g];
            c1[1] = *(const f32x4*)&sb1[32*w + 16 + 4*g];
            c1[0] = mfma6(A1[0], B0, c1[0]);
            c1[1] = mfma6(A1[1], B0, c1[1]);

            // silu -> sx1[b][j] (own j-slice; consumed only by own wave)
            #pragma unroll
            for (int mt = 0; mt < 2; ++mt) {
                f32x4 v;
                v.x = silu_f(c1[mt].x); v.y = silu_f(c1[mt].y);
                v.z = silu_f(c1[mt].z); v.w = silu_f(c1[mt].w);
                *(f32x4*)&sx1[l15][32*w + 16*mt + 4*g] = v;
            }

            // ---- layer 2: read own k-slice, split, 8 Mtiles of MFMA ----
            f32x4 r0 = *(const f32x4*)&sx1[l15][32*w + 8*g];
            f32x4 r1 = *(const f32x4*)&sx1[l15][32*w + 8*g + 4];
            short8v B2[3];
            {
                float xr[8] = {r0.x, r0.y, r0.z, r0.w, r1.x, r1.y, r1.z, r1.w};
                #pragma unroll
                for (int e = 0; e < 8; ++e) {
                    short t0, t1, t2; split3(xr[e], t0, t1, t2);
                    B2[0][e] = t0; B2[1][e] = t1; B2[2][e] = t2;
                }
            }
            f32x4 c2[8];
            #pragma unroll
            for (int mt = 0; mt < 8; ++mt) {
                f32x4 z = {0,0,0,0};
                c2[mt] = mfma6(A2[mt], B2, z);
            }
            #pragma unroll
            for (int mt = 0; mt < 8; ++mt)
                *(f32x4*)&sx2p[w][l15][16*mt + 4*g] = c2[mt];
            __syncthreads();

            // ---- reduce partials on own k-slice, + b2, silu, split -> B3 ----
            f32x4 xa = {0,0,0,0}, xb = {0,0,0,0};
            #pragma unroll
            for (int w2 = 0; w2 < 4; ++w2) {
                xa += *(const f32x4*)&sx2p[w2][l15][32*w + 8*g];
                xb += *(const f32x4*)&sx2p[w2][l15][32*w + 8*g + 4];
            }
            xa += *(const f32x4*)&sb2[32*w + 8*g];
            xb += *(const f32x4*)&sb2[32*w + 8*g + 4];
            short8v B3[3];
            {
                float xr[8] = {silu_f(xa.x), silu_f(xa.y), silu_f(xa.z), silu_f(xa.w),
                               silu_f(xb.x), silu_f(xb.y), silu_f(xb.z), silu_f(xb.w)};
                #pragma unroll
                for (int e = 0; e < 8; ++e) {
                    short t0, t1, t2; split3(xr[e], t0, t1, t2);
                    B3[0][e] = t0; B3[1][e] = t1; B3[2][e] = t2;
                }
            }

            // ---- layer 3 partial (rows j'<4 valid) ----
            f32x4 c3 = {0,0,0,0};
            c3 = mfma6(A3, B3, c3);
            if (g == 0) *(f32x4*)&sk3[w][l15][0] = c3;
            __syncthreads();

            f32x4 ks = b3v;
            #pragma unroll
            for (int w2 = 0; w2 < 4; ++w2)
                ks += *(const f32x4*)&sk3[w2][l15][0];

            const float wgt = (s == 1 || s == 2) ? 0.375f : 0.125f;
            hnew += ks * wgt;
            if (s == 0)      k1  = ks;
            else if (s == 1) k2  = ks;
            else if (s == 2) k3v = ks;
        }
        h += hnew;
    }

    if (tid < 16)
        *(f32x4*)&out[(size_t)(rowbase + l15) * 4] = h;
}

extern "C" void kernel_launch(void* const* d_in, const int* in_sizes, int n_in,
                              void* d_out, int out_size, void* d_ws, size_t ws_size,
                              hipStream_t stream)
{
    const float* quat = (const float*)d_in[0];
    const float* W1   = (const float*)d_in[1];
    const float* b1   = (const float*)d_in[2];
    const float* W2   = (const float*)d_in[3];
    const float* b2   = (const float*)d_in[4];
    const float* W3   = (const float*)d_in[5];
    const float* b3   = (const float*)d_in[6];
    float* out        = (float*)d_out;

    const int B = in_sizes[0] / (TSTEPS * 4);   // 16384
    dim3 grid(B / 16), block(256);
    hipLaunchKernelGGL(odernn_mfma, grid, block, 0, stream,
                       quat, W1, b1, W2, b2, W3, b3, out);
}